// Round 6
// baseline (192.381 us; speedup 1.0000x reference)
//
#include <hip/hip_runtime.h>

#define EPS_LN 1e-5f
#define EPS_D  1e-8f
#define BIGD 3.402823466e+38f

typedef __attribute__((ext_vector_type(8))) short s16x8;
typedef __attribute__((ext_vector_type(4))) float f32x4;
typedef __attribute__((ext_vector_type(4))) unsigned short u16x4;

// ---------------- ws layout (bytes) ----------------
#define XC_OFF    0u          // 4096*256*4   coarse GEMM output
#define XH_OFF    4194304u    // 20480*256*2  x hi-plane (fine rows 0..16383, coarse +16384)
#define XL_OFF    14680064u   // 20480*256*2  x lo-plane
#define MU_OFF    25165824u   // 20480*4
#define RS_OFF    25247744u   // 20480*4
#define WGH_OFF   25329664u   // 256*256*2  (g1*W)^T hi   [n][k]
#define WGL_OFF   25460736u   //            (g1*W)^T lo
#define WUGH_OFF  25591808u   //            (g2*W_up)^T hi
#define WUGL_OFF  25722880u   //            (g2*W_up)^T lo
#define C12_OFF   25853952u   // 4*256 f32: [c1_fine, c2_fine, c1_coarse, c2_coarse]
#define CPS_OFF   25858048u   // 4096*16 sorted coarse (x,y,z,|c|^2)
#define IDXS_OFF  25923584u   // 4096*4
#define CST_OFF   25939968u   // 513*4
#define UPS_OFF   25944064u   // 16384*16 sorted fine (x,y,z,|u|^2)
#define USORT_OFF 26206208u   // 16384*4  sorted -> original fine index

// ---------------------------------------------------------------------------
// prep roles by blockIdx:
//  [0,640)   : LN row stats + raw-x truncation-split into bf16 hi/lo planes
//  [640,656) : W,W_up -> g-folded transposed hi/lo bf16 planes
//  656,657   : c1 = b_ln@W, c2 = g@W
//  658       : 8^3 grid binning of coarse points
//  659       : 8^3 grid binning of FINE points (spatial sort for topk)
// ---------------------------------------------------------------------------
__device__ __forceinline__ int cell_of(float px, float py, float pz) {
    int cx = (int)(px * 8.0f); cx = cx < 0 ? 0 : (cx > 7 ? 7 : cx);
    int cy = (int)(py * 8.0f); cy = cy < 0 ? 0 : (cy > 7 ? 7 : cy);
    int cz = (int)(pz * 8.0f); cz = cz < 0 ? 0 : (cz > 7 ? 7 : cz);
    return (cz * 8 + cy) * 8 + cx;
}

__global__ __launch_bounds__(256) void prep_kernel(
    const float* __restrict__ x_feat, const float* __restrict__ xup_feat,
    const float* __restrict__ x_pos, const float* __restrict__ xup_pos,
    const float* __restrict__ W, const float* __restrict__ W_up,
    const float* __restrict__ g1, const float* __restrict__ b1,
    const float* __restrict__ g2, const float* __restrict__ b2,
    float* __restrict__ mu, float* __restrict__ rs,
    unsigned short* __restrict__ xh, unsigned short* __restrict__ xl,
    unsigned short* __restrict__ wgh, unsigned short* __restrict__ wgl,
    unsigned short* __restrict__ wugh, unsigned short* __restrict__ wugl,
    float* __restrict__ c12,
    float4* __restrict__ cps, int* __restrict__ idxs, int* __restrict__ cellStart,
    float4* __restrict__ ups, int* __restrict__ usort)
{
    __shared__ int cnt[512];
    __shared__ int ofs[512];
    __shared__ int wpart[4];

    const int bid = blockIdx.x, tid = threadIdx.x;
    const int lane = tid & 63, wave = tid >> 6;

    if (bid < 640) {
        // ---- LN stats + split (memory-bound streaming) ----
        #pragma unroll
        for (int rr = 0; rr < 8; ++rr) {
            const int r = bid * 32 + wave * 8 + rr;
            const float* src = (r < 16384) ? (xup_feat + (size_t)r * 256)
                                           : (x_feat + (size_t)(r - 16384) * 256);
            const float4 v = ((const float4*)src)[lane];
            float s  = v.x + v.y + v.z + v.w;
            float ss = v.x*v.x + v.y*v.y + v.z*v.z + v.w*v.w;
            #pragma unroll
            for (int off = 1; off < 64; off <<= 1) {
                s  += __shfl_xor(s,  off);
                ss += __shfl_xor(ss, off);
            }
            if (lane == 0) {
                const float m   = s * (1.0f / 256.0f);
                const float var = ss * (1.0f / 256.0f) - m * m;
                mu[r] = m;
                rs[r] = rsqrtf(var + EPS_LN);
            }
            const float vv[4] = { v.x, v.y, v.z, v.w };
            u16x4 hv, lv;
            #pragma unroll
            for (int c = 0; c < 4; ++c) {
                const unsigned ua = __float_as_uint(vv[c]);
                hv[c] = (unsigned short)(ua >> 16);
                const float lo = vv[c] - __uint_as_float(ua & 0xFFFF0000u);
                lv[c] = (unsigned short)(__float_as_uint(lo) >> 16);
            }
            *(u16x4*)&xh[(size_t)r * 256 + lane * 4] = hv;
            *(u16x4*)&xl[(size_t)r * 256 + lane * 4] = lv;
        }
    } else if (bid < 656) {
        // ---- g-folded transposed weight planes ----
        const int mb = bid - 640;
        const float* src = (mb < 8) ? W : W_up;
        const float* g   = (mb < 8) ? g1 : g2;
        unsigned short* dh = (mb < 8) ? wgh : wugh;
        unsigned short* dl = (mb < 8) ? wgl : wugl;
        const int n  = (mb & 7) * 32 + (tid >> 3);
        const int kc = (tid & 7) * 32;
        for (int kk = 0; kk < 32; kk += 4) {
            u16x4 hv, lv;
            #pragma unroll
            for (int c = 0; c < 4; ++c) {
                const int k = kc + kk + c;
                const float wv = g[k] * src[(size_t)k * 256 + n];
                const unsigned ua = __float_as_uint(wv);
                hv[c] = (unsigned short)(ua >> 16);
                const float lo = wv - __uint_as_float(ua & 0xFFFF0000u);
                lv[c] = (unsigned short)(__float_as_uint(lo) >> 16);
            }
            *(u16x4*)&dh[(size_t)n * 256 + kc + kk] = hv;
            *(u16x4*)&dl[(size_t)n * 256 + kc + kk] = lv;
        }
    } else if (bid < 658) {
        // ---- c1 = b_ln@W, c2 = g@W ----
        const bool fine = (bid == 657);
        const float* src = fine ? W_up : W;
        const float* g   = fine ? g2 : g1;
        const float* bln = fine ? b2 : b1;
        float* c1 = c12 + (fine ? 0 : 512);
        float* c2 = c12 + (fine ? 256 : 768);
        float a1 = 0.0f, a2 = 0.0f;
        for (int k = 0; k < 256; ++k) {
            const float wv = src[(size_t)k * 256 + tid];
            a1 = fmaf(bln[k], wv, a1);
            a2 = fmaf(g[k],   wv, a2);
        }
        c1[tid] = a1;
        c2[tid] = a2;
    } else {
        // ---- grid binning (count -> scan -> scatter), coarse or fine ----
        const bool fine = (bid == 659);
        const int npts = fine ? 16384 : 4096;
        const float* pos = fine ? xup_pos : x_pos;

        cnt[tid] = 0; cnt[tid + 256] = 0;
        __syncthreads();
        for (int i = tid; i < npts; i += 256) {
            const int c = cell_of(pos[i*3+0], pos[i*3+1], pos[i*3+2]);
            atomicAdd(&cnt[c], 1);
        }
        __syncthreads();
        // scan over 512 cells: wave w owns [w*128, w*128+128), lane owns 2
        const int base = wave * 128 + lane * 2;
        const int a = cnt[base], b = cnt[base + 1];
        const int p = a + b;
        int incl = p;
        #pragma unroll
        for (int off = 1; off < 64; off <<= 1) {
            const int t = __shfl_up(incl, off);
            if (lane >= off) incl += t;
        }
        if (lane == 63) wpart[wave] = incl;
        __syncthreads();
        int woff = 0;
        for (int w = 0; w < 4; ++w) if (w < wave) woff += wpart[w];
        const int e0 = woff + (incl - p);
        ofs[base] = e0;          ofs[base + 1] = e0 + a;
        if (!fine) {
            cellStart[base] = e0;    cellStart[base + 1] = e0 + a;
            if (tid == 0) cellStart[512] = 4096;
        }
        __syncthreads();
        for (int i = tid; i < npts; i += 256) {
            const float px = pos[i*3+0], py = pos[i*3+1], pz = pos[i*3+2];
            const int c = cell_of(px, py, pz);
            const int slot = atomicAdd(&ofs[c], 1);
            if (fine) {
                ups[slot] = make_float4(px, py, pz, px*px + py*py + pz*pz);
                usort[slot] = i;
            } else {
                cps[slot] = make_float4(px, py, pz, px*px + py*py + pz*pz);
                idxs[slot] = i;
            }
        }
    }
}

// ---------------------------------------------------------------------------
// gemm: S = x @ Wg via split-bf16 (hh+hl+lh), pure loads+MFMA inner loop.
// Epilogue: y = rs*S + (c1 - mu*rs*c2) + bias   (LN hoisted out as affine).
// blocks 0..255 fine (-> d_out), 256..319 coarse (-> xc).   [unchanged]
// ---------------------------------------------------------------------------
__global__ __launch_bounds__(256) void gemm_kernel(
    const unsigned short* __restrict__ xh, const unsigned short* __restrict__ xl,
    const float* __restrict__ mu, const float* __restrict__ rs,
    const unsigned short* __restrict__ wgh, const unsigned short* __restrict__ wgl,
    const unsigned short* __restrict__ wugh, const unsigned short* __restrict__ wugl,
    const float* __restrict__ c12,
    const float* __restrict__ b_up, const float* __restrict__ bb,
    float* __restrict__ outF, float* __restrict__ outC)
{
    const int bid = blockIdx.x;
    const unsigned short *BH, *BL; const float *c1, *c2, *bias; float* OUT;
    int row0, col0, statbase;
    if (bid < 256) {
        BH = wugh; BL = wugl; c1 = c12; c2 = c12 + 256; bias = b_up; OUT = outF;
        row0 = (bid >> 1) * 128; col0 = (bid & 1) * 128; statbase = 0;
    } else {
        const int id = bid - 256;
        BH = wgh; BL = wgl; c1 = c12 + 512; c2 = c12 + 768; bias = bb; OUT = outC;
        row0 = (id >> 1) * 128; col0 = (id & 1) * 128; statbase = 16384;
    }

    const int lane = threadIdx.x & 63;
    const int wave = threadIdx.x >> 6;
    const int wr = wave >> 1, wc = wave & 1;
    const int lm = lane & 15, lk = lane >> 4;

    int arow[4];
    #pragma unroll
    for (int mf = 0; mf < 4; ++mf)
        arow[mf] = statbase + row0 + wr * 64 + mf * 16 + lm;

    int ncol[4]; float c1v[4], c2v[4], bv[4];
    #pragma unroll
    for (int nf = 0; nf < 4; ++nf) {
        ncol[nf] = col0 + wc * 64 + nf * 16 + lm;
        c1v[nf] = c1[ncol[nf]];
        c2v[nf] = c2[ncol[nf]];
        bv[nf]  = bias[ncol[nf]];
    }

    f32x4 acc[4][4];
    #pragma unroll
    for (int mf = 0; mf < 4; ++mf)
        #pragma unroll
        for (int nf = 0; nf < 4; ++nf)
            acc[mf][nf] = (f32x4){0.0f, 0.0f, 0.0f, 0.0f};

    for (int k0 = 0; k0 < 256; k0 += 32) {
        const int kb = k0 + lk * 8;

        s16x8 bh[4], bl[4], ah[4], al[4];
        #pragma unroll
        for (int nf = 0; nf < 4; ++nf) {
            const size_t o = (size_t)ncol[nf] * 256 + kb;
            bh[nf] = *(const s16x8*)(BH + o);
            bl[nf] = *(const s16x8*)(BL + o);
        }
        #pragma unroll
        for (int mf = 0; mf < 4; ++mf) {
            const size_t o = (size_t)arow[mf] * 256 + kb;
            ah[mf] = *(const s16x8*)(xh + o);
            al[mf] = *(const s16x8*)(xl + o);
        }

        #pragma unroll
        for (int mf = 0; mf < 4; ++mf)
            #pragma unroll
            for (int nf = 0; nf < 4; ++nf) {
                acc[mf][nf] = __builtin_amdgcn_mfma_f32_16x16x32_bf16(ah[mf], bh[nf], acc[mf][nf], 0, 0, 0);
                acc[mf][nf] = __builtin_amdgcn_mfma_f32_16x16x32_bf16(ah[mf], bl[nf], acc[mf][nf], 0, 0, 0);
                acc[mf][nf] = __builtin_amdgcn_mfma_f32_16x16x32_bf16(al[mf], bh[nf], acc[mf][nf], 0, 0, 0);
            }
    }

    #pragma unroll
    for (int mf = 0; mf < 4; ++mf) {
        #pragma unroll
        for (int q = 0; q < 4; ++q) {
            const int orow = row0 + wr * 64 + mf * 16 + lk * 4 + q;
            const float m = mu[statbase + orow];
            const float s = rs[statbase + orow];
            const float ms = -m * s;
            #pragma unroll
            for (int nf = 0; nf < 4; ++nf)
                OUT[(size_t)orow * 256 + ncol[nf]] =
                    fmaf(s, acc[mf][nf][q], fmaf(ms, c2v[nf], c1v[nf]) + bv[nf]);
        }
    }
}

// ---------------------------------------------------------------------------
// topk: grid 3-NN over SPATIALLY SORTED fine points.
// Block = 256 thr (4 waves), su = bid*64 + lane (sorted index): lanes in a
// wave are spatial neighbors -> near-uniform cps loads, uniform trip counts.
// Wave w scans cells cc = w..26 step 4; LDS merge; exact fallback; gather+add
// to out[usort[su]].
// ---------------------------------------------------------------------------
__device__ __forceinline__ void ins3(float d, int p,
    float& b0, float& b1, float& b2, int& p0, int& p1, int& p2)
{
    const bool lt0 = d < b0, lt1 = d < b1, lt2 = d < b2;
    const float n1 = lt0 ? b0 : (lt1 ? d : b1);
    const int   q1 = lt0 ? p0 : (lt1 ? p : p1);
    const float n2 = lt1 ? b1 : (lt2 ? d : b2);
    const int   q2 = lt1 ? p1 : (lt2 ? p : p2);
    b0 = lt0 ? d : b0;  p0 = lt0 ? p : p0;
    b1 = n1; p1 = q1;
    b2 = n2; p2 = q2;
}

__global__ __launch_bounds__(256) void topk_kernel(
    const float4* __restrict__ cps, const int* __restrict__ idxs,
    const int* __restrict__ cellStart,
    const float4* __restrict__ ups, const int* __restrict__ usort,
    const float* __restrict__ xc, float* __restrict__ out)
{
    __shared__ float pd[4][64][3];
    __shared__ int   pp[4][64][3];
    __shared__ float wsel[64][3];
    __shared__ int   isel[64][3];
    __shared__ int   uor[64];
    __shared__ int   cst[513];

    const int tid = threadIdx.x, lane = tid & 63, wave = tid >> 6;
    const int su = blockIdx.x * 64 + lane;

    for (int i = tid; i < 513; i += 256) cst[i] = cellStart[i];

    const float4 up = ups[su];
    const float ux = up.x, uy = up.y, uz = up.z, uu = up.w;
    if (wave == 0) uor[lane] = usort[su];
    int cx = (int)(ux * 8.0f); cx = cx < 0 ? 0 : (cx > 7 ? 7 : cx);
    int cy = (int)(uy * 8.0f); cy = cy < 0 ? 0 : (cy > 7 ? 7 : cy);
    int cz = (int)(uz * 8.0f); cz = cz < 0 ? 0 : (cz > 7 ? 7 : cz);

    __syncthreads();

    float b0 = BIGD, b1 = BIGD, b2 = BIGD;
    int p0 = 0, p1 = 0, p2 = 0;

    for (int cc = wave; cc < 27; cc += 4) {
        const int nx = cx + (cc % 3) - 1;
        const int ny = cy + ((cc / 3) % 3) - 1;
        const int nz = cz + (cc / 9) - 1;
        if ((unsigned)nx > 7u || (unsigned)ny > 7u || (unsigned)nz > 7u) continue;
        const int cell = (nz * 8 + ny) * 8 + nx;
        const int s = cst[cell], e = cst[cell + 1];
        if (s >= e) continue;
        float4 c = cps[s];
        for (int p = s; p < e; ++p) {
            const float4 nxt = (p + 1 < e) ? cps[p + 1] : c;
            const float dot = ux * c.x + uy * c.y + uz * c.z;
            const float d = (uu - 2.0f * dot) + c.w;
            ins3(d, p, b0, b1, b2, p0, p1, p2);
            c = nxt;
        }
    }

    pd[wave][lane][0] = b0; pd[wave][lane][1] = b1; pd[wave][lane][2] = b2;
    pp[wave][lane][0] = p0; pp[wave][lane][1] = p1; pp[wave][lane][2] = p2;
    __syncthreads();

    if (wave == 0) {
        for (int w = 1; w < 4; ++w) {
            #pragma unroll
            for (int e = 0; e < 3; ++e)
                ins3(pd[w][lane][e], pp[w][lane][e], b0, b1, b2, p0, p1, p2);
        }

        // exact coverage guarantee (domain walls are safe: no points outside)
        const float h = 0.125f;
        float gmin = BIGD;
        if (cx > 0) gmin = fminf(gmin, ux - (float)(cx - 1) * h);
        if (cx < 7) gmin = fminf(gmin, (float)(cx + 2) * h - ux);
        if (cy > 0) gmin = fminf(gmin, uy - (float)(cy - 1) * h);
        if (cy < 7) gmin = fminf(gmin, (float)(cy + 2) * h - uy);
        if (cz > 0) gmin = fminf(gmin, uz - (float)(cz - 1) * h);
        if (cz < 7) gmin = fminf(gmin, (float)(cz + 2) * h - uz);

        if (b2 > gmin * gmin) {   // ~never taken; exact brute-force fallback
            b0 = b1 = b2 = BIGD; p0 = p1 = p2 = 0;
            for (int p = 0; p < 4096; ++p) {
                const float4 c = cps[p];
                const float dot = ux * c.x + uy * c.y + uz * c.z;
                const float d = (uu - 2.0f * dot) + c.w;
                ins3(d, p, b0, b1, b2, p0, p1, p2);
            }
        }

        float w0 = 1.0f / (b0 + EPS_D);
        float w1 = 1.0f / (b1 + EPS_D);
        float w2 = 1.0f / (b2 + EPS_D);
        const float inv = 1.0f / (w0 + w1 + w2);
        wsel[lane][0] = w0 * inv; wsel[lane][1] = w1 * inv; wsel[lane][2] = w2 * inv;
        isel[lane][0] = idxs[p0]; isel[lane][1] = idxs[p1]; isel[lane][2] = idxs[p2];
    }
    __syncthreads();

    // gather + weighted add: wave handles 16 u's, lane owns one float4 column
    #pragma unroll
    for (int r = 0; r < 16; ++r) {
        const int ul = wave * 16 + r;
        const float w0 = wsel[ul][0], w1 = wsel[ul][1], w2 = wsel[ul][2];
        const int a0 = isel[ul][0], a1 = isel[ul][1], a2 = isel[ul][2];
        const float4 v0 = ((const float4*)(xc + (size_t)a0 * 256))[lane];
        const float4 v1 = ((const float4*)(xc + (size_t)a1 * 256))[lane];
        const float4 v2 = ((const float4*)(xc + (size_t)a2 * 256))[lane];
        float4* op = (float4*)(out + (size_t)uor[ul] * 256);
        float4 o = op[lane];
        o.x += w0 * v0.x + w1 * v1.x + w2 * v2.x;
        o.y += w0 * v0.y + w1 * v1.y + w2 * v2.y;
        o.z += w0 * v0.z + w1 * v1.z + w2 * v2.z;
        o.w += w0 * v0.w + w1 * v1.w + w2 * v2.w;
        op[lane] = o;
    }
}

// ---------------------------------------------------------------------------
extern "C" void kernel_launch(void* const* d_in, const int* in_sizes, int n_in,
                              void* d_out, int out_size, void* d_ws, size_t ws_size,
                              hipStream_t stream)
{
    const float* x_feat   = (const float*)d_in[0];
    const float* x_pos    = (const float*)d_in[1];
    const float* xup_feat = (const float*)d_in[2];
    const float* xup_pos  = (const float*)d_in[3];
    const float* g1       = (const float*)d_in[4];
    const float* b1       = (const float*)d_in[5];
    const float* W        = (const float*)d_in[6];
    const float* bb       = (const float*)d_in[7];
    const float* g2       = (const float*)d_in[8];
    const float* b2       = (const float*)d_in[9];
    const float* W_up     = (const float*)d_in[10];
    const float* b_up     = (const float*)d_in[11];

    float* out = (float*)d_out;
    char*  ws  = (char*)d_ws;

    float* xc  = (float*)(ws + XC_OFF);
    unsigned short* xh   = (unsigned short*)(ws + XH_OFF);
    unsigned short* xl   = (unsigned short*)(ws + XL_OFF);
    float* mu  = (float*)(ws + MU_OFF);
    float* rs  = (float*)(ws + RS_OFF);
    unsigned short* wgh  = (unsigned short*)(ws + WGH_OFF);
    unsigned short* wgl  = (unsigned short*)(ws + WGL_OFF);
    unsigned short* wugh = (unsigned short*)(ws + WUGH_OFF);
    unsigned short* wugl = (unsigned short*)(ws + WUGL_OFF);
    float* c12 = (float*)(ws + C12_OFF);
    float4* cps = (float4*)(ws + CPS_OFF);
    int* idxs   = (int*)(ws + IDXS_OFF);
    int* cstart = (int*)(ws + CST_OFF);
    float4* ups = (float4*)(ws + UPS_OFF);
    int* usort  = (int*)(ws + USORT_OFF);

    prep_kernel<<<660, 256, 0, stream>>>(x_feat, xup_feat, x_pos, xup_pos,
                                         W, W_up, g1, b1, g2, b2,
                                         mu, rs, xh, xl,
                                         wgh, wgl, wugh, wugl,
                                         c12, cps, idxs, cstart, ups, usort);
    gemm_kernel<<<320, 256, 0, stream>>>(xh, xl, mu, rs,
                                         wgh, wgl, wugh, wugl,
                                         c12, b_up, bb, out, xc);
    topk_kernel<<<256, 256, 0, stream>>>(cps, idxs, cstart, ups, usort, xc, out);
}

// Round 7
// 180.452 us; speedup vs baseline: 1.0661x; 1.0661x over previous
//
#include <hip/hip_runtime.h>

#define EPS_LN 1e-5f
#define EPS_D  1e-8f
#define BIGD 3.402823466e+38f

typedef __attribute__((ext_vector_type(8))) short s16x8;
typedef __attribute__((ext_vector_type(4))) float f32x4;
typedef __attribute__((ext_vector_type(4))) unsigned short u16x4;

// ---------------- ws layout (bytes) ----------------
#define XC_OFF    0u          // 4096*256*4   coarse GEMM output
#define XH_OFF    4194304u    // 20480*256*2  x hi-plane (fine rows 0..16383, coarse +16384)
#define XL_OFF    14680064u   // 20480*256*2  x lo-plane
#define MU_OFF    25165824u   // 20480*4
#define RS_OFF    25247744u   // 20480*4
#define WGH_OFF   25329664u   // 256*256*2  (g1*W)^T hi   [n][k]
#define WGL_OFF   25460736u   //            (g1*W)^T lo
#define WUGH_OFF  25591808u   //            (g2*W_up)^T hi
#define WUGL_OFF  25722880u   //            (g2*W_up)^T lo
#define C12_OFF   25853952u   // 4*256 f32: [c1_fine, c2_fine, c1_coarse, c2_coarse]
#define CPS_OFF   25858048u   // 4096*16 sorted coarse (x,y,z,|c|^2)
#define IDXS_OFF  25923584u   // 4096*4
#define CST_OFF   25939968u   // 513*4
#define UPS_OFF   25944064u   // 16384*16 sorted fine (x,y,z,|u|^2)
#define USORT_OFF 26206208u   // 16384*4  sorted -> original fine index

// ---------------------------------------------------------------------------
// prep, 1024-thread blocks; SMALL/SERIAL roles first so they overlap the
// streaming blocks instead of trailing them (R6: 5% occupancy serial tail):
//  0      : fine-point binning  (16 iters, 16 waves)
//  1      : coarse-point binning (4 iters)
//  2,3    : c12 (c1=b_ln@W, c2=g@W), 4-way k-split + LDS reduce
//  4..7   : W,W_up -> g-folded transposed hi/lo bf16 planes
//  8..167 : LN row stats + raw-x truncation-split (128 rows/block)
// ---------------------------------------------------------------------------
__device__ __forceinline__ int cell_of(float px, float py, float pz) {
    int cx = (int)(px * 8.0f); cx = cx < 0 ? 0 : (cx > 7 ? 7 : cx);
    int cy = (int)(py * 8.0f); cy = cy < 0 ? 0 : (cy > 7 ? 7 : cy);
    int cz = (int)(pz * 8.0f); cz = cz < 0 ? 0 : (cz > 7 ? 7 : cz);
    return (cz * 8 + cy) * 8 + cx;
}

__global__ __launch_bounds__(1024) void prep_kernel(
    const float* __restrict__ x_feat, const float* __restrict__ xup_feat,
    const float* __restrict__ x_pos, const float* __restrict__ xup_pos,
    const float* __restrict__ W, const float* __restrict__ W_up,
    const float* __restrict__ g1, const float* __restrict__ b1,
    const float* __restrict__ g2, const float* __restrict__ b2,
    float* __restrict__ mu, float* __restrict__ rs,
    unsigned short* __restrict__ xh, unsigned short* __restrict__ xl,
    unsigned short* __restrict__ wgh, unsigned short* __restrict__ wgl,
    unsigned short* __restrict__ wugh, unsigned short* __restrict__ wugl,
    float* __restrict__ c12,
    float4* __restrict__ cps, int* __restrict__ idxs, int* __restrict__ cellStart,
    float4* __restrict__ ups, int* __restrict__ usort)
{
    __shared__ float smemf[2048];          // c12 reduce: [2][4][256]
    int* const cnt   = (int*)smemf;        // binning: cnt[512], ofs[512]
    int* const ofs   = ((int*)smemf) + 512;
    __shared__ int wpart[8];
    __shared__ int wpref[8];

    const int bid = blockIdx.x, tid = threadIdx.x;
    const int lane = tid & 63, wave = tid >> 6;

    if (bid < 2) {
        // ---- grid binning (count -> scan -> scatter) ----
        const bool fine = (bid == 0);
        const int npts = fine ? 16384 : 4096;
        const float* pos = fine ? xup_pos : x_pos;

        if (tid < 512) cnt[tid] = 0;
        __syncthreads();
        for (int i = tid; i < npts; i += 1024) {
            const int c = cell_of(pos[i*3+0], pos[i*3+1], pos[i*3+2]);
            atomicAdd(&cnt[c], 1);
        }
        __syncthreads();
        // scan: waves 0..7, lane owns cell = wave*64 + lane
        int v = 0, incl = 0;
        if (wave < 8) {
            const int cell = wave * 64 + lane;
            v = cnt[cell];
            incl = v;
            #pragma unroll
            for (int off = 1; off < 64; off <<= 1) {
                const int t = __shfl_up(incl, off);
                if (lane >= off) incl += t;
            }
            if (lane == 63) wpart[wave] = incl;
        }
        __syncthreads();
        if (tid == 0) {
            int run = 0;
            #pragma unroll
            for (int w = 0; w < 8; ++w) { wpref[w] = run; run += wpart[w]; }
        }
        __syncthreads();
        if (wave < 8) {
            const int cell = wave * 64 + lane;
            const int excl = incl - v + wpref[wave];
            ofs[cell] = excl;
            if (!fine) cellStart[cell] = excl;
        }
        if (!fine && tid == 0) cellStart[512] = 4096;
        __syncthreads();
        for (int i = tid; i < npts; i += 1024) {
            const float px = pos[i*3+0], py = pos[i*3+1], pz = pos[i*3+2];
            const int c = cell_of(px, py, pz);
            const int slot = atomicAdd(&ofs[c], 1);
            if (fine) {
                ups[slot] = make_float4(px, py, pz, px*px + py*py + pz*pz);
                usort[slot] = i;
            } else {
                cps[slot] = make_float4(px, py, pz, px*px + py*py + pz*pz);
                idxs[slot] = i;
            }
        }
    } else if (bid < 4) {
        // ---- c12: c1 = b_ln@W, c2 = g@W (4-way k-split, LDS reduce) ----
        const bool fine = (bid == 2);
        const float* src = fine ? W_up : W;
        const float* g   = fine ? g2 : g1;
        const float* bln = fine ? b2 : b1;
        float* c1 = c12 + (fine ? 0 : 512);
        float* c2 = c12 + (fine ? 256 : 768);
        const int col = tid & 255, kg = tid >> 8;
        float a1 = 0.0f, a2 = 0.0f;
        for (int k = kg * 64; k < kg * 64 + 64; ++k) {
            const float wv = src[(size_t)k * 256 + col];
            a1 = fmaf(bln[k], wv, a1);
            a2 = fmaf(g[k],   wv, a2);
        }
        smemf[kg * 256 + col] = a1;
        smemf[1024 + kg * 256 + col] = a2;
        __syncthreads();
        if (kg == 0) {
            c1[col] = smemf[col] + smemf[256 + col] + smemf[512 + col] + smemf[768 + col];
            c2[col] = smemf[1024 + col] + smemf[1280 + col] + smemf[1536 + col] + smemf[1792 + col];
        }
    } else if (bid < 8) {
        // ---- g-folded transposed weight planes (4 sub-blocks each) ----
        const int mb = (bid - 4) * 4 + (tid >> 8);        // 0..15
        const int t = tid & 255;
        const float* src = (mb < 8) ? W : W_up;
        const float* g   = (mb < 8) ? g1 : g2;
        unsigned short* dh = (mb < 8) ? wgh : wugh;
        unsigned short* dl = (mb < 8) ? wgl : wugl;
        const int n  = (mb & 7) * 32 + (t >> 3);
        const int kc = (t & 7) * 32;
        for (int kk = 0; kk < 32; kk += 4) {
            u16x4 hv, lv;
            #pragma unroll
            for (int c = 0; c < 4; ++c) {
                const int k = kc + kk + c;
                const float wv = g[k] * src[(size_t)k * 256 + n];
                const unsigned ua = __float_as_uint(wv);
                hv[c] = (unsigned short)(ua >> 16);
                const float lo = wv - __uint_as_float(ua & 0xFFFF0000u);
                lv[c] = (unsigned short)(__float_as_uint(lo) >> 16);
            }
            *(u16x4*)&dh[(size_t)n * 256 + kc + kk] = hv;
            *(u16x4*)&dl[(size_t)n * 256 + kc + kk] = lv;
        }
    } else {
        // ---- LN stats + split: 128 rows per block (16 waves x 8 rows) ----
        const int rbase = (bid - 8) * 128 + wave * 8;
        #pragma unroll
        for (int rr = 0; rr < 8; ++rr) {
            const int r = rbase + rr;
            const float* src = (r < 16384) ? (xup_feat + (size_t)r * 256)
                                           : (x_feat + (size_t)(r - 16384) * 256);
            const float4 v = ((const float4*)src)[lane];
            float s  = v.x + v.y + v.z + v.w;
            float ss = v.x*v.x + v.y*v.y + v.z*v.z + v.w*v.w;
            #pragma unroll
            for (int off = 1; off < 64; off <<= 1) {
                s  += __shfl_xor(s,  off);
                ss += __shfl_xor(ss, off);
            }
            if (lane == 0) {
                const float m   = s * (1.0f / 256.0f);
                const float var = ss * (1.0f / 256.0f) - m * m;
                mu[r] = m;
                rs[r] = rsqrtf(var + EPS_LN);
            }
            const float vv[4] = { v.x, v.y, v.z, v.w };
            u16x4 hv, lv;
            #pragma unroll
            for (int c = 0; c < 4; ++c) {
                const unsigned ua = __float_as_uint(vv[c]);
                hv[c] = (unsigned short)(ua >> 16);
                const float lo = vv[c] - __uint_as_float(ua & 0xFFFF0000u);
                lv[c] = (unsigned short)(__float_as_uint(lo) >> 16);
            }
            *(u16x4*)&xh[(size_t)r * 256 + lane * 4] = hv;
            *(u16x4*)&xl[(size_t)r * 256 + lane * 4] = lv;
        }
    }
}

// ---------------------------------------------------------------------------
// gemm: S = x @ Wg via split-bf16 (hh+hl+lh), pure loads+MFMA inner loop.
// Epilogue: y = rs*S + (c1 - mu*rs*c2) + bias.   [unchanged]
// ---------------------------------------------------------------------------
__global__ __launch_bounds__(256) void gemm_kernel(
    const unsigned short* __restrict__ xh, const unsigned short* __restrict__ xl,
    const float* __restrict__ mu, const float* __restrict__ rs,
    const unsigned short* __restrict__ wgh, const unsigned short* __restrict__ wgl,
    const unsigned short* __restrict__ wugh, const unsigned short* __restrict__ wugl,
    const float* __restrict__ c12,
    const float* __restrict__ b_up, const float* __restrict__ bb,
    float* __restrict__ outF, float* __restrict__ outC)
{
    const int bid = blockIdx.x;
    const unsigned short *BH, *BL; const float *c1, *c2, *bias; float* OUT;
    int row0, col0, statbase;
    if (bid < 256) {
        BH = wugh; BL = wugl; c1 = c12; c2 = c12 + 256; bias = b_up; OUT = outF;
        row0 = (bid >> 1) * 128; col0 = (bid & 1) * 128; statbase = 0;
    } else {
        const int id = bid - 256;
        BH = wgh; BL = wgl; c1 = c12 + 512; c2 = c12 + 768; bias = bb; OUT = outC;
        row0 = (id >> 1) * 128; col0 = (id & 1) * 128; statbase = 16384;
    }

    const int lane = threadIdx.x & 63;
    const int wave = threadIdx.x >> 6;
    const int wr = wave >> 1, wc = wave & 1;
    const int lm = lane & 15, lk = lane >> 4;

    int arow[4];
    #pragma unroll
    for (int mf = 0; mf < 4; ++mf)
        arow[mf] = statbase + row0 + wr * 64 + mf * 16 + lm;

    int ncol[4]; float c1v[4], c2v[4], bv[4];
    #pragma unroll
    for (int nf = 0; nf < 4; ++nf) {
        ncol[nf] = col0 + wc * 64 + nf * 16 + lm;
        c1v[nf] = c1[ncol[nf]];
        c2v[nf] = c2[ncol[nf]];
        bv[nf]  = bias[ncol[nf]];
    }

    f32x4 acc[4][4];
    #pragma unroll
    for (int mf = 0; mf < 4; ++mf)
        #pragma unroll
        for (int nf = 0; nf < 4; ++nf)
            acc[mf][nf] = (f32x4){0.0f, 0.0f, 0.0f, 0.0f};

    for (int k0 = 0; k0 < 256; k0 += 32) {
        const int kb = k0 + lk * 8;

        s16x8 bh[4], bl[4], ah[4], al[4];
        #pragma unroll
        for (int nf = 0; nf < 4; ++nf) {
            const size_t o = (size_t)ncol[nf] * 256 + kb;
            bh[nf] = *(const s16x8*)(BH + o);
            bl[nf] = *(const s16x8*)(BL + o);
        }
        #pragma unroll
        for (int mf = 0; mf < 4; ++mf) {
            const size_t o = (size_t)arow[mf] * 256 + kb;
            ah[mf] = *(const s16x8*)(xh + o);
            al[mf] = *(const s16x8*)(xl + o);
        }

        #pragma unroll
        for (int mf = 0; mf < 4; ++mf)
            #pragma unroll
            for (int nf = 0; nf < 4; ++nf) {
                acc[mf][nf] = __builtin_amdgcn_mfma_f32_16x16x32_bf16(ah[mf], bh[nf], acc[mf][nf], 0, 0, 0);
                acc[mf][nf] = __builtin_amdgcn_mfma_f32_16x16x32_bf16(ah[mf], bl[nf], acc[mf][nf], 0, 0, 0);
                acc[mf][nf] = __builtin_amdgcn_mfma_f32_16x16x32_bf16(al[mf], bh[nf], acc[mf][nf], 0, 0, 0);
            }
    }

    #pragma unroll
    for (int mf = 0; mf < 4; ++mf) {
        #pragma unroll
        for (int q = 0; q < 4; ++q) {
            const int orow = row0 + wr * 64 + mf * 16 + lk * 4 + q;
            const float m = mu[statbase + orow];
            const float s = rs[statbase + orow];
            const float ms = -m * s;
            #pragma unroll
            for (int nf = 0; nf < 4; ++nf)
                OUT[(size_t)orow * 256 + ncol[nf]] =
                    fmaf(s, acc[mf][nf][q], fmaf(ms, c2v[nf], c1v[nf]) + bv[nf]);
        }
    }
}

// ---------------------------------------------------------------------------
// topk: grid 3-NN over spatially sorted fine points.   [unchanged from R6]
// ---------------------------------------------------------------------------
__device__ __forceinline__ void ins3(float d, int p,
    float& b0, float& b1, float& b2, int& p0, int& p1, int& p2)
{
    const bool lt0 = d < b0, lt1 = d < b1, lt2 = d < b2;
    const float n1 = lt0 ? b0 : (lt1 ? d : b1);
    const int   q1 = lt0 ? p0 : (lt1 ? p : p1);
    const float n2 = lt1 ? b1 : (lt2 ? d : b2);
    const int   q2 = lt1 ? p1 : (lt2 ? p : p2);
    b0 = lt0 ? d : b0;  p0 = lt0 ? p : p0;
    b1 = n1; p1 = q1;
    b2 = n2; p2 = q2;
}

__global__ __launch_bounds__(256) void topk_kernel(
    const float4* __restrict__ cps, const int* __restrict__ idxs,
    const int* __restrict__ cellStart,
    const float4* __restrict__ ups, const int* __restrict__ usort,
    const float* __restrict__ xc, float* __restrict__ out)
{
    __shared__ float pd[4][64][3];
    __shared__ int   pp[4][64][3];
    __shared__ float wsel[64][3];
    __shared__ int   isel[64][3];
    __shared__ int   uor[64];
    __shared__ int   cst[513];

    const int tid = threadIdx.x, lane = tid & 63, wave = tid >> 6;
    const int su = blockIdx.x * 64 + lane;

    for (int i = tid; i < 513; i += 256) cst[i] = cellStart[i];

    const float4 up = ups[su];
    const float ux = up.x, uy = up.y, uz = up.z, uu = up.w;
    if (wave == 0) uor[lane] = usort[su];
    int cx = (int)(ux * 8.0f); cx = cx < 0 ? 0 : (cx > 7 ? 7 : cx);
    int cy = (int)(uy * 8.0f); cy = cy < 0 ? 0 : (cy > 7 ? 7 : cy);
    int cz = (int)(uz * 8.0f); cz = cz < 0 ? 0 : (cz > 7 ? 7 : cz);

    __syncthreads();

    float b0 = BIGD, b1 = BIGD, b2 = BIGD;
    int p0 = 0, p1 = 0, p2 = 0;

    for (int cc = wave; cc < 27; cc += 4) {
        const int nx = cx + (cc % 3) - 1;
        const int ny = cy + ((cc / 3) % 3) - 1;
        const int nz = cz + (cc / 9) - 1;
        if ((unsigned)nx > 7u || (unsigned)ny > 7u || (unsigned)nz > 7u) continue;
        const int cell = (nz * 8 + ny) * 8 + nx;
        const int s = cst[cell], e = cst[cell + 1];
        if (s >= e) continue;
        float4 c = cps[s];
        for (int p = s; p < e; ++p) {
            const float4 nxt = (p + 1 < e) ? cps[p + 1] : c;
            const float dot = ux * c.x + uy * c.y + uz * c.z;
            const float d = (uu - 2.0f * dot) + c.w;
            ins3(d, p, b0, b1, b2, p0, p1, p2);
            c = nxt;
        }
    }

    pd[wave][lane][0] = b0; pd[wave][lane][1] = b1; pd[wave][lane][2] = b2;
    pp[wave][lane][0] = p0; pp[wave][lane][1] = p1; pp[wave][lane][2] = p2;
    __syncthreads();

    if (wave == 0) {
        for (int w = 1; w < 4; ++w) {
            #pragma unroll
            for (int e = 0; e < 3; ++e)
                ins3(pd[w][lane][e], pp[w][lane][e], b0, b1, b2, p0, p1, p2);
        }

        const float h = 0.125f;
        float gmin = BIGD;
        if (cx > 0) gmin = fminf(gmin, ux - (float)(cx - 1) * h);
        if (cx < 7) gmin = fminf(gmin, (float)(cx + 2) * h - ux);
        if (cy > 0) gmin = fminf(gmin, uy - (float)(cy - 1) * h);
        if (cy < 7) gmin = fminf(gmin, (float)(cy + 2) * h - uy);
        if (cz > 0) gmin = fminf(gmin, uz - (float)(cz - 1) * h);
        if (cz < 7) gmin = fminf(gmin, (float)(cz + 2) * h - uz);

        if (b2 > gmin * gmin) {   // P ~ e^-30; exact fallback
            b0 = b1 = b2 = BIGD; p0 = p1 = p2 = 0;
            for (int p = 0; p < 4096; ++p) {
                const float4 c = cps[p];
                const float dot = ux * c.x + uy * c.y + uz * c.z;
                const float d = (uu - 2.0f * dot) + c.w;
                ins3(d, p, b0, b1, b2, p0, p1, p2);
            }
        }

        float w0 = 1.0f / (b0 + EPS_D);
        float w1 = 1.0f / (b1 + EPS_D);
        float w2 = 1.0f / (b2 + EPS_D);
        const float inv = 1.0f / (w0 + w1 + w2);
        wsel[lane][0] = w0 * inv; wsel[lane][1] = w1 * inv; wsel[lane][2] = w2 * inv;
        isel[lane][0] = idxs[p0]; isel[lane][1] = idxs[p1]; isel[lane][2] = idxs[p2];
    }
    __syncthreads();

    #pragma unroll
    for (int r = 0; r < 16; ++r) {
        const int ul = wave * 16 + r;
        const float w0 = wsel[ul][0], w1 = wsel[ul][1], w2 = wsel[ul][2];
        const int a0 = isel[ul][0], a1 = isel[ul][1], a2 = isel[ul][2];
        const float4 v0 = ((const float4*)(xc + (size_t)a0 * 256))[lane];
        const float4 v1 = ((const float4*)(xc + (size_t)a1 * 256))[lane];
        const float4 v2 = ((const float4*)(xc + (size_t)a2 * 256))[lane];
        float4* op = (float4*)(out + (size_t)uor[ul] * 256);
        float4 o = op[lane];
        o.x += w0 * v0.x + w1 * v1.x + w2 * v2.x;
        o.y += w0 * v0.y + w1 * v1.y + w2 * v2.y;
        o.z += w0 * v0.z + w1 * v1.z + w2 * v2.z;
        o.w += w0 * v0.w + w1 * v1.w + w2 * v2.w;
        op[lane] = o;
    }
}

// ---------------------------------------------------------------------------
extern "C" void kernel_launch(void* const* d_in, const int* in_sizes, int n_in,
                              void* d_out, int out_size, void* d_ws, size_t ws_size,
                              hipStream_t stream)
{
    const float* x_feat   = (const float*)d_in[0];
    const float* x_pos    = (const float*)d_in[1];
    const float* xup_feat = (const float*)d_in[2];
    const float* xup_pos  = (const float*)d_in[3];
    const float* g1       = (const float*)d_in[4];
    const float* b1       = (const float*)d_in[5];
    const float* W        = (const float*)d_in[6];
    const float* bb       = (const float*)d_in[7];
    const float* g2       = (const float*)d_in[8];
    const float* b2       = (const float*)d_in[9];
    const float* W_up     = (const float*)d_in[10];
    const float* b_up     = (const float*)d_in[11];

    float* out = (float*)d_out;
    char*  ws  = (char*)d_ws;

    float* xc  = (float*)(ws + XC_OFF);
    unsigned short* xh   = (unsigned short*)(ws + XH_OFF);
    unsigned short* xl   = (unsigned short*)(ws + XL_OFF);
    float* mu  = (float*)(ws + MU_OFF);
    float* rs  = (float*)(ws + RS_OFF);
    unsigned short* wgh  = (unsigned short*)(ws + WGH_OFF);
    unsigned short* wgl  = (unsigned short*)(ws + WGL_OFF);
    unsigned short* wugh = (unsigned short*)(ws + WUGH_OFF);
    unsigned short* wugl = (unsigned short*)(ws + WUGL_OFF);
    float* c12 = (float*)(ws + C12_OFF);
    float4* cps = (float4*)(ws + CPS_OFF);
    int* idxs   = (int*)(ws + IDXS_OFF);
    int* cstart = (int*)(ws + CST_OFF);
    float4* ups = (float4*)(ws + UPS_OFF);
    int* usort  = (int*)(ws + USORT_OFF);

    prep_kernel<<<168, 1024, 0, stream>>>(x_feat, xup_feat, x_pos, xup_pos,
                                          W, W_up, g1, b1, g2, b2,
                                          mu, rs, xh, xl,
                                          wgh, wgl, wugh, wugl,
                                          c12, cps, idxs, cstart, ups, usort);
    gemm_kernel<<<320, 256, 0, stream>>>(xh, xl, mu, rs,
                                         wgh, wgl, wugh, wugl,
                                         c12, b_up, bb, out, xc);
    topk_kernel<<<256, 256, 0, stream>>>(cps, idxs, cstart, ups, usort, xc, out);
}